// Round 16
// baseline (120.559 us; speedup 1.0000x reference)
//
#include <hip/hip_runtime.h>
#include <math.h>

// CMCV3Loss: B=512, S=8, D=128, H=64. Inputs: 4 x (4096x128 fp32), seq_len.
// fp8(e4m3fn)-MFMA symmetric grams; loss_row = lse_{m!=n} - pos (pos in fp32).
// Fixed max-shift: ex = exp2(fma(s, C1EXP, -C1EXP)); quantized sims <= ~1.02, safe.
// 3 launches: k_prep, k_gram, k_tail. Harness floor ~50us (268MB ws re-poison).
// R16: R15 structure (the reproduced optimum) with fp8 operands — halves
// fragment bytes (8B/lane) so one dwordx4 carries TWO K-steps (k, k+32 packed);
// per temporal tile 16 loads (was 32), L2 traffic ~41MB (was 82). MFMA count
// unchanged (non-scaled fp8 = bf16 rate). Attacks the measured binding
// resource: load issue count + L2 latency exposure (k_gram ~23% busy).
//
// ws float offsets:
#define CTR_L1 0        // 8 counters, stride 32 floats (k_tail arrival)
#define CTR_L2 2048     // single second-level counter
#define RS_T   49152    // temporal rowsums [4][4096]
#define RS_C   65536    // contrastive rowsums [4 calls][8 p][1024]
#define SLOT   98304    // slots stride 32: 0..7 c-log, 8..15 t-log, 16..23 ortho, 24 posC, 25 posT
// ws byte offsets (fp8 arrays, fragment-major, 512KB per input each):
// zf8 [4 in][256 G=row>>4][pair:1][quad:2][slot:4][16B]  bytes0-7: k=p*64+q*8+j, bytes8-15: +32
#define ZF_BYTE 397312
// zh8 [4 in][8 p][32 G=b>>4][half:1][quad:2][slot:4][16B]  half0: cols q*8+j (sh-norm), half1: cols 64+q*8+j (pv-norm); bytes8-15: +32
#define ZH8_BYTE 2494464

#define INV_T 14.285714285714286f
#define C1EXP 20.609929155556627f   // INV_T * log2(e)
#define EPS_N 1e-8f
#define NBLK_TAIL 192                // 8 groups x 24

typedef __attribute__((ext_vector_type(4))) float floatx4;

__device__ __forceinline__ const float* pick4(const float* a, const float* b,
                                              const float* c, const float* d, int i) {
    return i == 0 ? a : i == 1 ? b : i == 2 ? c : d;
}

// fp32 -> OCP e4m3fn, RNE, saturate at 448, subnormals handled.
__device__ __forceinline__ unsigned f2e4m3(float x) {
    unsigned u = __float_as_uint(x);
    unsigned s = (u >> 24) & 0x80;
    u &= 0x7fffffffu;
    if (u >= 0x43e00000u) return s | 0x7e;            // >= 448: saturate
    if (u < 0x3c800000u) {                            // < 2^-6: subnormal
        int m = (int)rintf(__uint_as_float(u) * 512.0f);   // units of 2^-9, 0..8
        return s | (unsigned)m;                       // m==8 encodes min normal
    }
    unsigned r = u + 0x7ffffu + ((u >> 20) & 1u);     // RNE to 3 mantissa bits
    int e = (int)((r >> 23) & 0xffu) - 127;
    if (e > 8) return s | 0x7e;
    return s | (unsigned)(((e + 7) << 3) | ((r >> 20) & 7u));
}

__device__ __forceinline__ unsigned pack4_e4m3(const float* p, float sc) {
    return f2e4m3(p[0] * sc) | (f2e4m3(p[1] * sc) << 8)
         | (f2e4m3(p[2] * sc) << 16) | (f2e4m3(p[3] * sc) << 24);
}

// ---------- prep: blocks 0..127 = fragment-major fp8 convert (full-line writes);
//                  blocks 128..639 = per-sequence dots + zeroing ----------
__global__ __launch_bounds__(256) void k_prep(const float* __restrict__ in0, const float* __restrict__ in1,
                                              const float* __restrict__ in2, const float* __restrict__ in3,
                                              float* __restrict__ ws) {
    __shared__ float ivf[128], ivs[128], ivp[128];   // convert branch
    __shared__ float buf[4][8][128];                 // dots branch
    __shared__ float iv[3][32];
    __shared__ float red[3];
    const int tid = threadIdx.x;
    const int blk = blockIdx.x;

    if (blk < 128) {
        const int input = blk >> 5, g = blk & 31;    // 128 rows: g*128..+128
        const float* src = pick4(in0, in1, in2, in3, input) + (size_t)(g * 128) * 128;
        {
            int r = tid >> 1, half = tid & 1;
            const float* rp_ = src + r * 128 + half * 64;
            float ss = 0.0f;
            #pragma unroll
            for (int k = 0; k < 16; k++) {
                float4 x = *(const float4*)(rp_ + k * 4);
                ss = fmaf(x.x, x.x, fmaf(x.y, x.y, fmaf(x.z, x.z, fmaf(x.w, x.w, ss))));
            }
            float other = __shfl_xor(ss, 1);
            if (half == 0) {
                ivs[r] = 1.0f / fmaxf(sqrtf(ss), EPS_N);
                ivf[r] = 1.0f / fmaxf(sqrtf(ss + other), EPS_N);
            } else {
                ivp[r] = 1.0f / fmaxf(sqrtf(ss), EPS_N);
            }
        }
        __syncthreads();

        unsigned char* zf8 = (unsigned char*)ws + ZF_BYTE + (size_t)input * 524288 + (size_t)g * 16384;
        unsigned char* zh8 = (unsigned char*)ws + ZH8_BYTE + (size_t)input * 524288;
        #pragma unroll
        for (int it = 0; it < 4; it++) {             // zf8: 1024 chunks [gg:3][p:1][q:2][slot:4]
            int ch = it * 256 + tid;
            int gg = ch >> 7, p = (ch >> 6) & 1, q = (ch >> 4) & 3, slot = ch & 15;
            int lr = gg * 16 + slot;
            int k0 = p * 64 + q * 8;
            const float* sp = src + lr * 128 + k0;
            float sc = ivf[lr];
            int4 v;
            v.x = (int)pack4_e4m3(sp, sc);      v.y = (int)pack4_e4m3(sp + 4, sc);
            v.z = (int)pack4_e4m3(sp + 32, sc); v.w = (int)pack4_e4m3(sp + 36, sc);
            *(int4*)(zf8 + (size_t)ch * 16) = v;
        }
        #pragma unroll
        for (int it = 0; it < 4; it++) {             // zh8: 1024 chunks [ps:3][h:1][q:2][slot:4]
            int ch = it * 256 + tid;
            int ps = ch >> 7, h = (ch >> 6) & 1, q = (ch >> 4) & 3, slot = ch & 15;
            int lr = slot * 8 + ps;                  // local row = seq slot * 8 + p
            int c0 = h * 64 + q * 8;
            const float* sp = src + lr * 128 + c0;
            float sc = h ? ivp[lr] : ivs[lr];
            int4 v;
            v.x = (int)pack4_e4m3(sp, sc);      v.y = (int)pack4_e4m3(sp + 4, sc);
            v.z = (int)pack4_e4m3(sp + 32, sc); v.w = (int)pack4_e4m3(sp + 36, sc);
            *(int4*)(zh8 + (size_t)ps * 65536 + (size_t)g * 2048 + (size_t)(ch & 127) * 16) = v;
        }
        return;
    }

    const int s = blk - 128;
    int gid = s * 256 + tid;
    if (gid < 2080) ws[gid] = 0.0f;
    if (gid < 50176) ws[RS_T + gid] = 0.0f;
    if (tid < 3) red[tid] = 0.0f;

    #pragma unroll
    for (int i = 0; i < 4; i++) {
        int e4 = tid + i * 256;
        int inp = e4 >> 8, row = (e4 >> 5) & 7, c4 = e4 & 31;
        float4 f = *(const float4*)(pick4(in0, in1, in2, in3, inp) + (size_t)(s * 8 + row) * 128 + c4 * 4);
        *(float4*)(&buf[inp][row][c4 * 4]) = f;
    }
    __syncthreads();
    {
        int row32 = tid >> 3, seg = tid & 7;
        const float* rp_ = &buf[row32 >> 3][row32 & 7][seg * 16];
        float ss = 0.0f;
        #pragma unroll
        for (int k = 0; k < 4; k++) {
            float4 x = *(const float4*)(rp_ + k * 4);
            ss = fmaf(x.x, x.x, fmaf(x.y, x.y, fmaf(x.z, x.z, fmaf(x.w, x.w, ss))));
        }
        ss += __shfl_xor(ss, 1); ss += __shfl_xor(ss, 2);
        float cross = __shfl_xor(ss, 4);
        if (seg == 0) {
            iv[0][row32] = 1.0f / fmaxf(sqrtf(ss), EPS_N);
            iv[2][row32] = 1.0f / fmaxf(sqrtf(ss + cross), EPS_N);
        }
        if (seg == 4) iv[1][row32] = 1.0f / fmaxf(sqrtf(ss), EPS_N);
    }
    __syncthreads();

    float val = 0.0f;
    int cat = -1;
    if (tid < 48) {
        const int oa[6]  = {0, 2, 1, 3, 0, 1};
        const int oaf[6] = {0, 0, 0, 0, 64, 64};
        const int ob[6]  = {0, 2, 1, 3, 2, 3};
        int term = tid >> 3, row = tid & 7;
        const float* A = &buf[oa[term]][row][oaf[term]];
        const float* B = &buf[ob[term]][row][64];
        float d = 0.0f;
        #pragma unroll
        for (int k = 0; k < 16; k++) {
            float4 x = *(const float4*)(A + k * 4);
            float4 y = *(const float4*)(B + k * 4);
            d = fmaf(x.x, y.x, fmaf(x.y, y.y, fmaf(x.z, y.z, fmaf(x.w, y.w, d))));
        }
        float ia = iv[oaf[term] ? 1 : 0][oa[term] * 8 + row];
        float ib = iv[1][ob[term] * 8 + row];
        val = fmaxf(d * ia * ib, 0.0f);
        cat = 2;
    } else if (tid < 80) {
        const int ca[4] = {0, 1, 0, 2}, cb[4] = {2, 3, 1, 3}, coff[4] = {0, 0, 64, 64};
        int call = (tid - 48) >> 3, row = (tid - 48) & 7;
        const float* A = &buf[ca[call]][row][coff[call]];
        const float* B = &buf[cb[call]][row][coff[call]];
        float d = 0.0f;
        #pragma unroll
        for (int k = 0; k < 16; k++) {
            float4 x = *(const float4*)(A + k * 4);
            float4 y = *(const float4*)(B + k * 4);
            d = fmaf(x.x, y.x, fmaf(x.y, y.y, fmaf(x.z, y.z, fmaf(x.w, y.w, d))));
        }
        int ivb = coff[call] ? 1 : 0;
        val = d * iv[ivb][ca[call] * 8 + row] * iv[ivb][cb[call] * 8 + row];
        cat = 0;
    } else if (tid < 136) {
        int u = tid - 80;
        int inp = u / 14, v = u % 14, pp = v >> 1, half = v & 1;
        int ra = (pp == 0) ? 1 : (pp + 1);
        const float* A = &buf[inp][ra][half * 64];
        const float* B = &buf[inp][0][half * 64];
        float d = 0.0f;
        #pragma unroll
        for (int k = 0; k < 16; k++) {
            float4 x = *(const float4*)(A + k * 4);
            float4 y = *(const float4*)(B + k * 4);
            d = fmaf(x.x, y.x, fmaf(x.y, y.y, fmaf(x.z, y.z, fmaf(x.w, y.w, d))));
        }
        float wgt = (pp == 0) ? 2.0f : 1.0f;
        val = d * wgt * iv[2][inp * 8 + ra] * iv[2][inp * 8];
        cat = 1;
    }
    if (cat >= 0) atomicAdd(&red[cat], val);
    __syncthreads();
    if (tid == 0) atomicAdd(ws + SLOT + 32 * 24, red[0]);
    if (tid == 1) atomicAdd(ws + SLOT + 32 * 25, red[1]);
    if (tid == 2) atomicAdd(ws + SLOT + 32 * (16 + (s & 7)), red[2]);
}

// ---------- multi-tile symmetric gram (R11/R15 structure, fp8 operands) ----------
// blocks [0,1024): temporal — input = b>>8, rt = (b>>3)&31, chunk = b&7:
//   tiles j = chunk*2 + t (t=0,1), plus j=16 when chunk==7 && rt<16. j=0 diag.
// blocks [1024,1280): contrastive — c = b-1024: call = c>>6, p = (c>>3)&7, rt = c&7:
//   tiles j = 0..3, plus j=4 when rt<4.
__global__ __launch_bounds__(256, 3) void k_gram(float* __restrict__ ws) {
    const int tid = threadIdx.x;
    const int b = blockIdx.x;
    const int w = tid >> 6, lane = tid & 63, quad = (tid >> 4) & 3, l15 = tid & 15;
    const int wrow = (w >> 1) * 64, wcol = (w & 1) * 64;
    const int laneoff = quad * 256 + l15 * 16;       // bytes within a (G[,half],pair)

    const char* aPtr;
    const char* planeA;
    const char* planeB;
    int npair, ntiles, jbase, modm, hoff;
    float* rsR;
    float* rsCbase;
    bool temporal = (b < 1024);
    int rt;

    if (temporal) {
        int input = b >> 8;
        rt = (b >> 3) & 31;
        int chunk = b & 7;
        const char* zf8 = (const char*)ws + ZF_BYTE + (size_t)input * 524288;
        planeA = planeB = zf8;
        hoff = 0;
        aPtr = zf8 + (size_t)(rt * 8 + (wrow >> 4)) * 2048 + laneoff;
        npair = 2; modm = 31;
        jbase = chunk * 2;
        ntiles = 2 + ((chunk == 7 && rt < 16) ? 1 : 0);
        rsR = ws + RS_T + input * 4096 + rt * 128;
        rsCbase = ws + RS_T + input * 4096;
    } else {
        int c = b - 1024;
        int call = c >> 6, p = (c >> 3) & 7;
        rt = c & 7;
        const int ca[4] = {0, 1, 0, 2}, cb[4] = {2, 3, 1, 3};
        hoff = (call >= 2) ? 1024 : 0;               // half offset inside a G block
        const char* zh8 = (const char*)ws + ZH8_BYTE;
        planeA = zh8 + (size_t)ca[call] * 524288 + (size_t)p * 65536;
        planeB = zh8 + (size_t)cb[call] * 524288 + (size_t)p * 65536;
        const char* rpl = (rt < 4) ? planeA : planeB;
        aPtr = rpl + (size_t)((rt & 3) * 8 + (wrow >> 4)) * 2048 + hoff + laneoff;
        npair = 1; modm = 7;
        jbase = 0;
        ntiles = (rt < 4) ? 5 : 4;
        rsR = ws + RS_C + (call * 8 + p) * 1024 + rt * 128;
        rsCbase = ws + RS_C + (call * 8 + p) * 1024;
    }

    float rp_acc[16];
    #pragma unroll
    for (int i = 0; i < 16; i++) rp_acc[i] = 0.0f;

    for (int t = 0; t < ntiles; t++) {
        int j = (temporal && t == 2) ? 16 : (jbase + t);
        int ct = (rt + j) & modm;
        bool diag = (j == 0);
        const char* bPtr;
        if (temporal) {
            bPtr = planeA + (size_t)(ct * 8 + (wcol >> 4)) * 2048 + laneoff;
        } else {
            const char* cpl = (ct < 4) ? planeA : planeB;
            bPtr = cpl + (size_t)((ct & 3) * 8 + (wcol >> 4)) * 2048 + hoff + laneoff;
        }

        floatx4 acc[4][4];
        #pragma unroll
        for (int ri = 0; ri < 4; ri++)
            #pragma unroll
            for (int ci = 0; ci < 4; ci++) acc[ri][ci] = (floatx4){0.f, 0.f, 0.f, 0.f};

        for (int p = 0; p < npair; p++) {
            longlong2 av[4], bv[4];
            #pragma unroll
            for (int i = 0; i < 4; i++) {
                av[i] = *(const longlong2*)(aPtr + (size_t)i * 2048 + p * 1024);
                bv[i] = *(const longlong2*)(bPtr + (size_t)i * 2048 + p * 1024);
            }
            #pragma unroll
            for (int h = 0; h < 2; h++) {            // .x = ksb even (k), .y = ksb odd (k+32)
                #pragma unroll
                for (int ri = 0; ri < 4; ri++)
                    #pragma unroll
                    for (int ci = 0; ci < 4; ci++)
                        acc[ri][ci] = __builtin_amdgcn_mfma_f32_16x16x32_fp8_fp8(
                            h ? av[ri].y : av[ri].x, h ? bv[ci].y : bv[ci].x,
                            acc[ri][ci], 0, 0, 0);
            }
        }

        if (diag) {
            #pragma unroll
            for (int ri = 0; ri < 4; ri++) {
                #pragma unroll
                for (int reg = 0; reg < 4; reg++) {
                    int rloc = wrow + ri * 16 + quad * 4 + reg;
                    float rp = 0.f;
                    #pragma unroll
                    for (int ci = 0; ci < 4; ci++) {
                        int cloc = wcol + ci * 16 + l15;
                        float ex = __builtin_amdgcn_exp2f(fmaf(acc[ri][ci][reg], C1EXP, -C1EXP));
                        rp += (cloc != rloc) ? ex : 0.f;   // exact diag exclusion
                    }
                    rp_acc[ri * 4 + reg] += rp;
                }
            }
        } else {
            float colp[4] = {0.f, 0.f, 0.f, 0.f};
            #pragma unroll
            for (int ri = 0; ri < 4; ri++) {
                #pragma unroll
                for (int reg = 0; reg < 4; reg++) {
                    float rp = 0.f;
                    #pragma unroll
                    for (int ci = 0; ci < 4; ci++) {
                        float ex = __builtin_amdgcn_exp2f(fmaf(acc[ri][ci][reg], C1EXP, -C1EXP));
                        rp += ex;
                        colp[ci] += ex;
                    }
                    rp_acc[ri * 4 + reg] += rp;
                }
            }
            float* rsC = rsCbase + ct * 128;
            #pragma unroll
            for (int ci = 0; ci < 4; ci++) {           // transpose contribution
                colp[ci] += __shfl_xor(colp[ci], 16);
                colp[ci] += __shfl_xor(colp[ci], 32);
                if (lane < 16) atomicAdd(rsC + wcol + ci * 16 + l15, colp[ci]);
            }
        }
    }

    // row-sum flush: once per block
    #pragma unroll
    for (int ri = 0; ri < 4; ri++) {
        #pragma unroll
        for (int reg = 0; reg < 4; reg++) {
            float rp = rp_acc[ri * 4 + reg];
            rp += __shfl_xor(rp, 1); rp += __shfl_xor(rp, 2);
            rp += __shfl_xor(rp, 4); rp += __shfl_xor(rp, 8);
            if (l15 == 0) atomicAdd(rsR + wrow + ri * 16 + quad * 4 + reg, rp);
        }
    }
}

// ---------- tail: grid-parallel logsum + arrival-gated final ----------
__global__ __launch_bounds__(256) void k_tail(float* __restrict__ ws, float* __restrict__ out) {
    __shared__ float tred[4];
    __shared__ int lastf;
    const int tid = threadIdx.x;
    const int b = blockIdx.x;
    const int idx = b * 256 + tid;       // blocks 0..63 temporal, 64..191 contrastive

    float l = __logf(ws[RS_T + idx]);
    #pragma unroll
    for (int m = 1; m < 64; m <<= 1) l += __shfl_xor(l, m);
    if ((tid & 63) == 0) tred[tid >> 6] = l;
    __syncthreads();
    if (tid == 0) {
        float bs = tred[0] + tred[1] + tred[2] + tred[3];
        int slot = (idx < 16384) ? (8 + (b & 7)) : (b & 7);
        atomicAdd(ws + SLOT + 32 * slot, bs);
    }
    __syncthreads();   // vmcnt(0): slot atomic completed before counter RMW
    if (tid == 0) {
        int last = 0;
        int o1 = __hip_atomic_fetch_add((int*)(ws + CTR_L1 + 32 * (b & 7)), 1,
                                        __ATOMIC_RELAXED, __HIP_MEMORY_SCOPE_AGENT);
        if (o1 == 23) {
            int o2 = __hip_atomic_fetch_add((int*)(ws + CTR_L2), 1,
                                            __ATOMIC_RELAXED, __HIP_MEMORY_SCOPE_AGENT);
            last = (o2 == 7);
        }
        lastf = last;
    }
    __syncthreads();
    if (!lastf) return;

    if (tid < 64) {
        float v2 = 0.0f;
        if (tid < 26) {
            float x = __hip_atomic_load(ws + SLOT + 32 * tid, __ATOMIC_RELAXED, __HIP_MEMORY_SCOPE_AGENT);
            float wgt;
            if (tid < 8)       wgt = 1.0f / 8192.0f;
            else if (tid < 24) wgt = 1.0f / 4096.0f;
            else if (tid == 24) wgt = -2.0f * INV_T / 8192.0f;
            else                wgt = -INV_T / 4096.0f;
            v2 = x * wgt;
        }
        #pragma unroll
        for (int m = 1; m < 64; m <<= 1) v2 += __shfl_xor(v2, m);
        if (tid == 0) out[0] = v2 + 8.0f * INV_T;
    }
}

extern "C" void kernel_launch(void* const* d_in, const int* in_sizes, int n_in,
                              void* d_out, int out_size, void* d_ws, size_t ws_size,
                              hipStream_t stream) {
    (void)in_sizes; (void)n_in; (void)out_size; (void)ws_size;
    const float* in0 = (const float*)d_in[0];
    const float* in1 = (const float*)d_in[1];
    const float* in2 = (const float*)d_in[2];
    const float* in3 = (const float*)d_in[3];
    float* ws = (float*)d_ws;
    float* out = (float*)d_out;

    hipLaunchKernelGGL(k_prep, dim3(640), dim3(256), 0, stream, in0, in1, in2, in3, ws);
    hipLaunchKernelGGL(k_gram, dim3(1280), dim3(256), 0, stream, ws);
    hipLaunchKernelGGL(k_tail, dim3(NBLK_TAIL), dim3(256), 0, stream, ws, out);
}

// Round 17
// 114.095 us; speedup vs baseline: 1.0567x; 1.0567x over previous
//
#include <hip/hip_runtime.h>
#include <math.h>

// CMCV3Loss: B=512, S=8, D=128, H=64. Inputs: 4 x (4096x128 fp32), seq_len.
// bf16-MFMA symmetric grams; loss_row = lse_{m!=n} - pos. Fixed max-shift:
// ex = exp((s-1)*INV_T) = exp2(fma(s, C1EXP, -C1EXP)) since s<=1 for normalized vecs.
// 3 launches: k_prep, k_gram, k_tail. Harness floor ~50us (268MB ws re-poison).
// R17 = FINAL: exact R15/R11 configuration — the measured optimum (114.3us).
// Falsified alternatives (all regressed or neutral): LDS staging ±swizzle (R8: 49us
// but barrier-bound), async global_load_lds (R8), direct-VGPR row-scatter (R9),
// wide per-block tile sweeps (R12: L2 thrash), XCD swizzle (R13: dispatch!=b%8),
// A-register caching (R12/13/14: launch-burst L2 thrash), fp8 operands (R16:
// neutral — binding resource is load latency, not bytes). Timed-loop top-5 is
// 100% harness fills at ~78% HBM peak; controllable region ~65us has no
// unfalsified >5% lever left.
//
// ws float offsets:
#define CTR_L1 0        // 8 counters, stride 32 floats (k_tail arrival)
#define CTR_L2 2048     // single second-level counter
#define RS_T   49152    // temporal rowsums [4][4096]
#define RS_C   65536    // contrastive rowsums [4 calls][8 p][1024]
#define SLOT   98304    // slots stride 32: 0..7 c-log, 8..15 t-log, 16..23 ortho, 24 posC, 25 posT
// ws byte offsets (bf16 arrays, fragment-major):
#define ZF_BYTE 397312   // zf [4 input][256 g][16 kc][16 slot][8]   row = g*16+slot
#define ZH_BYTE 4591616  // zh [4 input][8 p][32 g][16 kc][16 slot][8]  b = g*16+slot; kc<8 sh-norm, >=8 pv-norm

#define INV_T 14.285714285714286f
#define C1EXP 20.609929155556627f   // INV_T * log2(e)
#define EPS_N 1e-8f
#define NBLK_TAIL 192                // 8 groups x 24

typedef __attribute__((ext_vector_type(8))) short short8;
typedef __attribute__((ext_vector_type(4))) float floatx4;

__device__ __forceinline__ const float* pick4(const float* a, const float* b,
                                              const float* c, const float* d, int i) {
    return i == 0 ? a : i == 1 ? b : i == 2 ? c : d;
}

__device__ __forceinline__ unsigned short f2bf(float x) {
    unsigned u = __float_as_uint(x);
    u += 0x7fff + ((u >> 16) & 1);
    return (unsigned short)(u >> 16);
}

__device__ __forceinline__ ushort4 cvt4(float4 x, float sc) {
    ushort4 o;
    o.x = f2bf(x.x * sc); o.y = f2bf(x.y * sc); o.z = f2bf(x.z * sc); o.w = f2bf(x.w * sc);
    return o;
}

// ---------- prep: blocks 0..127 = fragment-major convert (full-line writes);
//                  blocks 128..639 = per-sequence dots + zeroing ----------
__global__ __launch_bounds__(256) void k_prep(const float* __restrict__ in0, const float* __restrict__ in1,
                                              const float* __restrict__ in2, const float* __restrict__ in3,
                                              float* __restrict__ ws) {
    __shared__ float ivf[128], ivs[128], ivp[128];   // convert branch
    __shared__ float buf[4][8][128];                 // dots branch
    __shared__ float iv[3][32];
    __shared__ float red[3];
    const int tid = threadIdx.x;
    const int blk = blockIdx.x;

    if (blk < 128) {
        const int input = blk >> 5, g = blk & 31;
        const float* src = pick4(in0, in1, in2, in3, input) + (size_t)(g * 128) * 128;
        {
            int r = tid >> 1, half = tid & 1;
            const float* rp_ = src + r * 128 + half * 64;
            float ss = 0.0f;
            #pragma unroll
            for (int k = 0; k < 16; k++) {
                float4 x = *(const float4*)(rp_ + k * 4);
                ss = fmaf(x.x, x.x, fmaf(x.y, x.y, fmaf(x.z, x.z, fmaf(x.w, x.w, ss))));
            }
            float other = __shfl_xor(ss, 1);
            if (half == 0) {
                ivs[r] = 1.0f / fmaxf(sqrtf(ss), EPS_N);
                ivf[r] = 1.0f / fmaxf(sqrtf(ss + other), EPS_N);
            } else {
                ivp[r] = 1.0f / fmaxf(sqrtf(ss), EPS_N);
            }
        }
        __syncthreads();
        unsigned short* zf = (unsigned short*)((char*)ws + ZF_BYTE) + (size_t)input * 524288 + (size_t)g * 16384;
        unsigned short* zh = (unsigned short*)((char*)ws + ZH_BYTE) + (size_t)input * 524288;
        #pragma unroll
        for (int k = 0; k < 8; k++) {            // zf: coalesced full-line writes
            int ch = k * 256 + tid;              // [gg:3][kc:4][slot:4]
            int lr = ((ch >> 8) << 4) | (ch & 15);
            int kc = (ch >> 4) & 15;
            const float* sp = src + lr * 128 + kc * 8;
            float sc = ivf[lr];
            *(ushort4*)(zf + ch * 8)     = cvt4(*(const float4*)sp, sc);
            *(ushort4*)(zf + ch * 8 + 4) = cvt4(*(const float4*)(sp + 4), sc);
        }
        #pragma unroll
        for (int k = 0; k < 8; k++) {            // zh: coalesced per p-region
            int ch = k * 256 + tid;              // [p:3][kc:4][slot:4]
            int p = ch >> 8, kc = (ch >> 4) & 15, slot = ch & 15;
            int lr = slot * 8 + p;
            const float* sp = src + lr * 128 + kc * 8;
            float sc = (kc < 8 ? ivs : ivp)[lr];
            unsigned short* dst = zh + (size_t)p * 65536 + (size_t)g * 2048 + (ch & 255) * 8;
            *(ushort4*)dst       = cvt4(*(const float4*)sp, sc);
            *(ushort4*)(dst + 4) = cvt4(*(const float4*)(sp + 4), sc);
        }
        return;
    }

    const int s = blk - 128;
    int gid = s * 256 + tid;
    if (gid < 2080) ws[gid] = 0.0f;
    if (gid < 50176) ws[RS_T + gid] = 0.0f;
    if (tid < 3) red[tid] = 0.0f;

    #pragma unroll
    for (int i = 0; i < 4; i++) {
        int e4 = tid + i * 256;
        int inp = e4 >> 8, row = (e4 >> 5) & 7, c4 = e4 & 31;
        float4 f = *(const float4*)(pick4(in0, in1, in2, in3, inp) + (size_t)(s * 8 + row) * 128 + c4 * 4);
        *(float4*)(&buf[inp][row][c4 * 4]) = f;
    }
    __syncthreads();
    {
        int row32 = tid >> 3, seg = tid & 7;
        const float* rp_ = &buf[row32 >> 3][row32 & 7][seg * 16];
        float ss = 0.0f;
        #pragma unroll
        for (int k = 0; k < 4; k++) {
            float4 x = *(const float4*)(rp_ + k * 4);
            ss = fmaf(x.x, x.x, fmaf(x.y, x.y, fmaf(x.z, x.z, fmaf(x.w, x.w, ss))));
        }
        ss += __shfl_xor(ss, 1); ss += __shfl_xor(ss, 2);
        float cross = __shfl_xor(ss, 4);
        if (seg == 0) {
            iv[0][row32] = 1.0f / fmaxf(sqrtf(ss), EPS_N);
            iv[2][row32] = 1.0f / fmaxf(sqrtf(ss + cross), EPS_N);
        }
        if (seg == 4) iv[1][row32] = 1.0f / fmaxf(sqrtf(ss), EPS_N);
    }
    __syncthreads();

    float val = 0.0f;
    int cat = -1;
    if (tid < 48) {
        const int oa[6]  = {0, 2, 1, 3, 0, 1};
        const int oaf[6] = {0, 0, 0, 0, 64, 64};
        const int ob[6]  = {0, 2, 1, 3, 2, 3};
        int term = tid >> 3, row = tid & 7;
        const float* A = &buf[oa[term]][row][oaf[term]];
        const float* B = &buf[ob[term]][row][64];
        float d = 0.0f;
        #pragma unroll
        for (int k = 0; k < 16; k++) {
            float4 x = *(const float4*)(A + k * 4);
            float4 y = *(const float4*)(B + k * 4);
            d = fmaf(x.x, y.x, fmaf(x.y, y.y, fmaf(x.z, y.z, fmaf(x.w, y.w, d))));
        }
        float ia = iv[oaf[term] ? 1 : 0][oa[term] * 8 + row];
        float ib = iv[1][ob[term] * 8 + row];
        val = fmaxf(d * ia * ib, 0.0f);
        cat = 2;
    } else if (tid < 80) {
        const int ca[4] = {0, 1, 0, 2}, cb[4] = {2, 3, 1, 3}, coff[4] = {0, 0, 64, 64};
        int call = (tid - 48) >> 3, row = (tid - 48) & 7;
        const float* A = &buf[ca[call]][row][coff[call]];
        const float* B = &buf[cb[call]][row][coff[call]];
        float d = 0.0f;
        #pragma unroll
        for (int k = 0; k < 16; k++) {
            float4 x = *(const float4*)(A + k * 4);
            float4 y = *(const float4*)(B + k * 4);
            d = fmaf(x.x, y.x, fmaf(x.y, y.y, fmaf(x.z, y.z, fmaf(x.w, y.w, d))));
        }
        int ivb = coff[call] ? 1 : 0;
        val = d * iv[ivb][ca[call] * 8 + row] * iv[ivb][cb[call] * 8 + row];
        cat = 0;
    } else if (tid < 136) {
        int u = tid - 80;
        int inp = u / 14, v = u % 14, pp = v >> 1, half = v & 1;
        int ra = (pp == 0) ? 1 : (pp + 1);
        const float* A = &buf[inp][ra][half * 64];
        const float* B = &buf[inp][0][half * 64];
        float d = 0.0f;
        #pragma unroll
        for (int k = 0; k < 16; k++) {
            float4 x = *(const float4*)(A + k * 4);
            float4 y = *(const float4*)(B + k * 4);
            d = fmaf(x.x, y.x, fmaf(x.y, y.y, fmaf(x.z, y.z, fmaf(x.w, y.w, d))));
        }
        float wgt = (pp == 0) ? 2.0f : 1.0f;
        val = d * wgt * iv[2][inp * 8 + ra] * iv[2][inp * 8];
        cat = 1;
    }
    if (cat >= 0) atomicAdd(&red[cat], val);
    __syncthreads();
    if (tid == 0) atomicAdd(ws + SLOT + 32 * 24, red[0]);
    if (tid == 1) atomicAdd(ws + SLOT + 32 * 25, red[1]);
    if (tid == 2) atomicAdd(ws + SLOT + 32 * (16 + (s & 7)), red[2]);
}

// ---------- multi-tile symmetric gram (R11): direct coalesced frag loads, register rowsums ----------
// blocks [0,1024): temporal — input = b>>8, rt = (b>>3)&31, chunk = b&7:
//   tiles j = chunk*2 + t (t=0,1), plus j=16 when chunk==7 && rt<16. j=0 diag.
// blocks [1024,1280): contrastive — c = b-1024: call = c>>6, p = (c>>3)&7, rt = c&7:
//   tiles j = 0..3, plus j=4 when rt<4.
__global__ __launch_bounds__(256, 3) void k_gram(float* __restrict__ ws) {
    const int tid = threadIdx.x;
    const int b = blockIdx.x;
    const int w = tid >> 6, lane = tid & 63, quad = (tid >> 4) & 3, l15 = tid & 15;
    const int wrow = (w >> 1) * 64, wcol = (w & 1) * 64;
    const int laneoff = (lane >> 4) * 128 + (lane & 15) * 8;   // shorts

    const short* aPtr;
    const short* planeA;     // for bPtr computation per ct
    const short* planeB;
    int nk, ntiles, jbase, modm;
    float* rsR;
    float* rsCbase;
    bool temporal = (b < 1024);
    int rt;

    if (temporal) {
        int input = b >> 8;
        rt = (b >> 3) & 31;
        int chunk = b & 7;
        const short* zf = (const short*)((const char*)ws + ZF_BYTE) + (size_t)input * 524288;
        planeA = planeB = zf;
        aPtr = zf + (rt * 8 + (wrow >> 4)) * 2048 + laneoff;
        nk = 2; modm = 31;
        jbase = chunk * 2;
        ntiles = 2 + ((chunk == 7 && rt < 16) ? 1 : 0);
        rsR = ws + RS_T + input * 4096 + rt * 128;
        rsCbase = ws + RS_T + input * 4096;
    } else {
        int c = b - 1024;
        int call = c >> 6, p = (c >> 3) & 7;
        rt = c & 7;
        const int ca[4] = {0, 1, 0, 2}, cb[4] = {2, 3, 1, 3};
        const int hb = (call >= 2) ? 8 : 0;
        const short* zh = (const short*)((const char*)ws + ZH_BYTE);
        planeA = zh + (size_t)ca[call] * 524288 + (size_t)p * 65536 + hb * 128;
        planeB = zh + (size_t)cb[call] * 524288 + (size_t)p * 65536 + hb * 128;
        const short* rpl = (rt < 4) ? planeA : planeB;
        aPtr = rpl + ((rt & 3) * 8 + (wrow >> 4)) * 2048 + laneoff;
        nk = 1; modm = 7;
        jbase = 0;
        ntiles = (rt < 4) ? 5 : 4;
        rsR = ws + RS_C + (call * 8 + p) * 1024 + rt * 128;
        rsCbase = ws + RS_C + (call * 8 + p) * 1024;
    }

    float rp_acc[16];
    #pragma unroll
    for (int i = 0; i < 16; i++) rp_acc[i] = 0.0f;

    for (int t = 0; t < ntiles; t++) {
        int j = (temporal && t == 2) ? 16 : (jbase + t);
        int ct = (rt + j) & modm;
        bool diag = (j == 0);
        const short* bPtr;
        if (temporal) {
            bPtr = planeA + (ct * 8 + (wcol >> 4)) * 2048 + laneoff;
        } else {
            const short* cpl = (ct < 4) ? planeA : planeB;
            bPtr = cpl + ((ct & 3) * 8 + (wcol >> 4)) * 2048 + laneoff;
        }

        floatx4 acc[4][4];
        #pragma unroll
        for (int ri = 0; ri < 4; ri++)
            #pragma unroll
            for (int ci = 0; ci < 4; ci++) acc[ri][ci] = (floatx4){0.f, 0.f, 0.f, 0.f};

        for (int ksb = 0; ksb < 2 * nk; ksb++) {
            const int koff = ksb * 512;
            short8 a[4], bb[4];
            #pragma unroll
            for (int i = 0; i < 4; i++) {
                a[i]  = *(const short8*)(aPtr + i * 2048 + koff);
                bb[i] = *(const short8*)(bPtr + i * 2048 + koff);
            }
            #pragma unroll
            for (int ri = 0; ri < 4; ri++)
                #pragma unroll
                for (int ci = 0; ci < 4; ci++)
                    acc[ri][ci] = __builtin_amdgcn_mfma_f32_16x16x32_bf16(a[ri], bb[ci], acc[ri][ci], 0, 0, 0);
        }

        if (diag) {
            #pragma unroll
            for (int ri = 0; ri < 4; ri++) {
                #pragma unroll
                for (int reg = 0; reg < 4; reg++) {
                    int rloc = wrow + ri * 16 + quad * 4 + reg;
                    float rp = 0.f;
                    #pragma unroll
                    for (int ci = 0; ci < 4; ci++) {
                        int cloc = wcol + ci * 16 + l15;
                        float ex = __builtin_amdgcn_exp2f(fmaf(acc[ri][ci][reg], C1EXP, -C1EXP));
                        rp += (cloc != rloc) ? ex : 0.f;   // exact diag exclusion
                    }
                    rp_acc[ri * 4 + reg] += rp;
                }
            }
        } else {
            float colp[4] = {0.f, 0.f, 0.f, 0.f};
            #pragma unroll
            for (int ri = 0; ri < 4; ri++) {
                #pragma unroll
                for (int reg = 0; reg < 4; reg++) {
                    float rp = 0.f;
                    #pragma unroll
                    for (int ci = 0; ci < 4; ci++) {
                        float ex = __builtin_amdgcn_exp2f(fmaf(acc[ri][ci][reg], C1EXP, -C1EXP));
                        rp += ex;
                        colp[ci] += ex;
                    }
                    rp_acc[ri * 4 + reg] += rp;
                }
            }
            float* rsC = rsCbase + ct * 128;
            #pragma unroll
            for (int ci = 0; ci < 4; ci++) {           // transpose contribution (per tile)
                colp[ci] += __shfl_xor(colp[ci], 16);
                colp[ci] += __shfl_xor(colp[ci], 32);
                if (lane < 16) atomicAdd(rsC + wcol + ci * 16 + l15, colp[ci]);
            }
        }
    }

    // row-sum flush: once per block
    #pragma unroll
    for (int ri = 0; ri < 4; ri++) {
        #pragma unroll
        for (int reg = 0; reg < 4; reg++) {
            float rp = rp_acc[ri * 4 + reg];
            rp += __shfl_xor(rp, 1); rp += __shfl_xor(rp, 2);
            rp += __shfl_xor(rp, 4); rp += __shfl_xor(rp, 8);
            if (l15 == 0) atomicAdd(rsR + wrow + ri * 16 + quad * 4 + reg, rp);
        }
    }
}

// ---------- tail: grid-parallel logsum + arrival-gated final ----------
__global__ __launch_bounds__(256) void k_tail(float* __restrict__ ws, float* __restrict__ out) {
    __shared__ float tred[4];
    __shared__ int lastf;
    const int tid = threadIdx.x;
    const int b = blockIdx.x;
    const int idx = b * 256 + tid;       // blocks 0..63 temporal, 64..191 contrastive

    float l = __logf(ws[RS_T + idx]);
    #pragma unroll
    for (int m = 1; m < 64; m <<= 1) l += __shfl_xor(l, m);
    if ((tid & 63) == 0) tred[tid >> 6] = l;
    __syncthreads();
    if (tid == 0) {
        float bs = tred[0] + tred[1] + tred[2] + tred[3];
        int slot = (idx < 16384) ? (8 + (b & 7)) : (b & 7);
        atomicAdd(ws + SLOT + 32 * slot, bs);
    }
    __syncthreads();   // vmcnt(0): slot atomic completed before counter RMW
    if (tid == 0) {
        int last = 0;
        int o1 = __hip_atomic_fetch_add((int*)(ws + CTR_L1 + 32 * (b & 7)), 1,
                                        __ATOMIC_RELAXED, __HIP_MEMORY_SCOPE_AGENT);
        if (o1 == 23) {
            int o2 = __hip_atomic_fetch_add((int*)(ws + CTR_L2), 1,
                                            __ATOMIC_RELAXED, __HIP_MEMORY_SCOPE_AGENT);
            last = (o2 == 7);
        }
        lastf = last;
    }
    __syncthreads();
    if (!lastf) return;

    if (tid < 64) {
        float v2 = 0.0f;
        if (tid < 26) {
            float x = __hip_atomic_load(ws + SLOT + 32 * tid, __ATOMIC_RELAXED, __HIP_MEMORY_SCOPE_AGENT);
            float wgt;
            if (tid < 8)       wgt = 1.0f / 8192.0f;
            else if (tid < 24) wgt = 1.0f / 4096.0f;
            else if (tid == 24) wgt = -2.0f * INV_T / 8192.0f;
            else                wgt = -INV_T / 4096.0f;
            v2 = x * wgt;
        }
        #pragma unroll
        for (int m = 1; m < 64; m <<= 1) v2 += __shfl_xor(v2, m);
        if (tid == 0) out[0] = v2 + 8.0f * INV_T;
    }
}

extern "C" void kernel_launch(void* const* d_in, const int* in_sizes, int n_in,
                              void* d_out, int out_size, void* d_ws, size_t ws_size,
                              hipStream_t stream) {
    (void)in_sizes; (void)n_in; (void)out_size; (void)ws_size;
    const float* in0 = (const float*)d_in[0];
    const float* in1 = (const float*)d_in[1];
    const float* in2 = (const float*)d_in[2];
    const float* in3 = (const float*)d_in[3];
    float* ws = (float*)d_ws;
    float* out = (float*)d_out;

    hipLaunchKernelGGL(k_prep, dim3(640), dim3(256), 0, stream, in0, in1, in2, in3, ws);
    hipLaunchKernelGGL(k_gram, dim3(1280), dim3(256), 0, stream, ws);
    hipLaunchKernelGGL(k_tail, dim3(NBLK_TAIL), dim3(256), 0, stream, ws, out);
}